// Round 3
// baseline (90.941 us; speedup 1.0000x reference)
//
#include <hip/hip_runtime.h>
#include <math.h>

#define B_ 2
#define SQ_ 1024
#define SK_ 1024
#define D_ 64
#define DV_ 64
#define QB 4
#define TPB 256
#define KSPLIT 4
#define KTILE (SK_ / KSPLIT)  // 256 keys per block
#define NEGC (-1e9f)

// ---------------- Kernel 1: per-split partial attention ----------------
// grid = B * (SQ/QB) * KSPLIT = 2048 blocks of 256 threads.
// Each block: 4 queries x 256 keys -> partial m, l, unnormalized o -> d_ws.
__global__ __launch_bounds__(TPB, 4) void manh_attn_part(
    const float* __restrict__ qg, const float* __restrict__ kg,
    const float* __restrict__ vg, const int* __restrict__ maskg,
    float* __restrict__ ws_o, float* __restrict__ ws_m,
    float* __restrict__ ws_l) {
  __shared__ float4 p4[KTILE];       // 4 KB probs, key-major [kk][4q]
  __shared__ float pv[16][QB][DV_];  // 16 KB PV chunk partials
  __shared__ float redm[4][QB];
  __shared__ float redl[4][QB];

  const int tid = threadIdx.x;
  const int split = blockIdx.x & (KSPLIT - 1);
  const int qgrp = (blockIdx.x >> 2) & 255;
  const int b = blockIdx.x >> 10;
  const int q0 = qgrp * QB;
  const int kbase = split * KTILE;

  const float4* kb4 = (const float4*)(kg + (size_t)b * SK_ * D_);
  const float4* qrow = (const float4*)(qg + ((size_t)b * SQ_ + q0) * D_);
  const int* mb = maskg + (size_t)b * SK_ + kbase;

  const int krow = tid >> 2;  // key within 64-key subtile
  const int qtr = tid & 3;    // dim quarter (16 dims = 4 float4)

  // q fragments in registers: this thread's dim-quarter of all 4 q rows.
  // Broadcast loads (4 distinct addresses/wave), L1-resident.
  float4 qr[QB][4];
#pragma unroll
  for (int qq = 0; qq < QB; ++qq)
#pragma unroll
    for (int j = 0; j < 4; ++j) qr[qq][j] = qrow[qq * 16 + (qtr << 2) + j];

  // ---- Phase 1: L1 distances. 4 subtiles x 64 keys; 4 lanes/key. ----
  float dall[4][QB];
#pragma unroll
  for (int s = 0; s < 4; ++s) {
    float4 k4[4];
#pragma unroll
    for (int j = 0; j < 4; ++j)
      k4[j] = kb4[(size_t)(kbase + s * 64 + krow) * 16 + (qtr << 2) + j];
    float dloc[QB];
#pragma unroll
    for (int qq = 0; qq < QB; ++qq) dloc[qq] = 0.f;
#pragma unroll
    for (int j = 0; j < 4; ++j) {
#pragma unroll
      for (int qq = 0; qq < QB; ++qq) {
        float4 a = qr[qq][j];
        float4 kk = k4[j];
        dloc[qq] += fabsf(a.x - kk.x) + fabsf(a.y - kk.y) +
                    fabsf(a.z - kk.z) + fabsf(a.w - kk.w);
      }
    }
    // combine the 4 dim-quarter partials (consecutive lanes 4k..4k+3)
#pragma unroll
    for (int qq = 0; qq < QB; ++qq) {
      float t = dloc[qq];
      t += __shfl_xor(t, 1, 64);
      t += __shfl_xor(t, 2, 64);
      dall[s][qq] = t;
    }
  }

  // lane-group member c owns subtile c's key krow: okey = c*64 + krow
  const int osub = tid & 3;
  const int okey = osub * 64 + krow;
  float sc[QB];
#pragma unroll
  for (int qq = 0; qq < QB; ++qq) {
    float t01 = (osub & 1) ? dall[1][qq] : dall[0][qq];
    float t23 = (osub & 1) ? dall[3][qq] : dall[2][qq];
    sc[qq] = (osub & 2) ? t23 : t01;
  }
  const int mk = mb[okey];

  float s_[QB], lmax[QB];
#pragma unroll
  for (int qq = 0; qq < QB; ++qq) {
    s_[qq] = (mk == 0) ? NEGC : -sc[qq];
    lmax[qq] = s_[qq];
  }
#pragma unroll
  for (int off = 32; off > 0; off >>= 1)
#pragma unroll
    for (int qq = 0; qq < QB; ++qq)
      lmax[qq] = fmaxf(lmax[qq], __shfl_down(lmax[qq], off, 64));
  if ((tid & 63) == 0)
#pragma unroll
    for (int qq = 0; qq < QB; ++qq) redm[tid >> 6][qq] = lmax[qq];
  __syncthreads();
  float m[QB];
#pragma unroll
  for (int qq = 0; qq < QB; ++qq)
    m[qq] = fmaxf(fmaxf(redm[0][qq], redm[1][qq]),
                  fmaxf(redm[2][qq], redm[3][qq]));

  float lsum[QB], e[QB];
#pragma unroll
  for (int qq = 0; qq < QB; ++qq) {
    e[qq] = __expf(s_[qq] - m[qq]);
    lsum[qq] = e[qq];
  }
  p4[okey] = make_float4(e[0], e[1], e[2], e[3]);
#pragma unroll
  for (int off = 32; off > 0; off >>= 1)
#pragma unroll
    for (int qq = 0; qq < QB; ++qq) lsum[qq] += __shfl_down(lsum[qq], off, 64);
  if ((tid & 63) == 0)
#pragma unroll
    for (int qq = 0; qq < QB; ++qq) redl[tid >> 6][qq] = lsum[qq];
  __syncthreads();  // covers p4 + redl

  // ---- Phase 2: PV over 256 keys ----
  const int col = tid & 15;
  const int chunk = tid >> 4;
  const float4* vb4 = (const float4*)(vg + (size_t)b * SK_ * DV_);
  float4 acc[QB];
#pragma unroll
  for (int qq = 0; qq < QB; ++qq) acc[qq] = make_float4(0.f, 0.f, 0.f, 0.f);
#pragma unroll 4
  for (int t = 0; t < 16; ++t) {
    const int kk = t * 16 + chunk;
    float4 v4 = vb4[(size_t)(kbase + kk) * 16 + col];
    float4 pw = p4[kk];
    acc[0].x += pw.x * v4.x; acc[0].y += pw.x * v4.y;
    acc[0].z += pw.x * v4.z; acc[0].w += pw.x * v4.w;
    acc[1].x += pw.y * v4.x; acc[1].y += pw.y * v4.y;
    acc[1].z += pw.y * v4.z; acc[1].w += pw.y * v4.w;
    acc[2].x += pw.z * v4.x; acc[2].y += pw.z * v4.y;
    acc[2].z += pw.z * v4.z; acc[2].w += pw.z * v4.w;
    acc[3].x += pw.w * v4.x; acc[3].y += pw.w * v4.y;
    acc[3].z += pw.w * v4.z; acc[3].w += pw.w * v4.w;
  }
#pragma unroll
  for (int qq = 0; qq < QB; ++qq) ((float4*)&pv[chunk][qq][0])[col] = acc[qq];
  __syncthreads();

  // partial outputs (unnormalized) + m/l to workspace
  float lt[QB];
#pragma unroll
  for (int qq = 0; qq < QB; ++qq)
    lt[qq] = redl[0][qq] + redl[1][qq] + redl[2][qq] + redl[3][qq];
  if (tid < QB) {
    const size_t row = (size_t)b * SQ_ + q0 + tid;
    ws_m[row * KSPLIT + split] = m[tid];
    ws_l[row * KSPLIT + split] = lt[tid];
  }
  const int q2 = tid >> 6;
  const int d2 = tid & 63;
  float so = 0.f;
#pragma unroll
  for (int c = 0; c < 16; ++c) so += pv[c][q2][d2];
  const size_t row = (size_t)b * SQ_ + q0 + q2;
  ws_o[(row * KSPLIT + split) * DV_ + d2] = so;
}

// ---------------- Kernel 2: combine the 4 splits ----------------
// grid = B*SQ/4 = 512 blocks of 256; each 64-lane group handles one row.
__global__ __launch_bounds__(TPB) void manh_attn_combine(
    const float* __restrict__ ws_o, const float* __restrict__ ws_m,
    const float* __restrict__ ws_l, float* __restrict__ outg) {
  const int tid = threadIdx.x;
  const size_t r = (size_t)blockIdx.x * 4 + (tid >> 6);
  const int d = tid & 63;
  const float m0 = ws_m[r * 4 + 0], m1 = ws_m[r * 4 + 1];
  const float m2 = ws_m[r * 4 + 2], m3 = ws_m[r * 4 + 3];
  const float l0 = ws_l[r * 4 + 0], l1 = ws_l[r * 4 + 1];
  const float l2 = ws_l[r * 4 + 2], l3 = ws_l[r * 4 + 3];
  const float gm = fmaxf(fmaxf(m0, m1), fmaxf(m2, m3));
  const float w0 = __expf(m0 - gm), w1 = __expf(m1 - gm);
  const float w2 = __expf(m2 - gm), w3 = __expf(m3 - gm);
  const float L = l0 * w0 + l1 * w1 + l2 * w2 + l3 * w3;
  const float acc = ws_o[(r * 4 + 0) * DV_ + d] * w0 +
                    ws_o[(r * 4 + 1) * DV_ + d] * w1 +
                    ws_o[(r * 4 + 2) * DV_ + d] * w2 +
                    ws_o[(r * 4 + 3) * DV_ + d] * w3;
  outg[r * DV_ + d] = acc / L;
}

extern "C" void kernel_launch(void* const* d_in, const int* in_sizes, int n_in,
                              void* d_out, int out_size, void* d_ws,
                              size_t ws_size, hipStream_t stream) {
  const float* q = (const float*)d_in[0];
  const float* k = (const float*)d_in[1];
  const float* v = (const float*)d_in[2];
  const int* mask = (const int*)d_in[3];
  float* out = (float*)d_out;

  float* ws = (float*)d_ws;
  float* ws_o = ws;                                  // B*SQ*KSPLIT*DV floats
  float* ws_m = ws + (size_t)B_ * SQ_ * KSPLIT * DV_;  // B*SQ*KSPLIT
  float* ws_l = ws_m + (size_t)B_ * SQ_ * KSPLIT;

  dim3 grid1(B_ * (SQ_ / QB) * KSPLIT);
  manh_attn_part<<<grid1, TPB, 0, stream>>>(q, k, v, mask, ws_o, ws_m, ws_l);
  dim3 grid2(B_ * SQ_ / 4);
  manh_attn_combine<<<grid2, TPB, 0, stream>>>(ws_o, ws_m, ws_l, out);
}

// Round 4
// 75.300 us; speedup vs baseline: 1.2077x; 1.2077x over previous
//
#include <hip/hip_runtime.h>
#include <math.h>

#define B_ 2
#define SQ_ 1024
#define SK_ 1024
#define D_ 64
#define DV_ 64
#define QB 4
#define NEGC (-1e9f)
#define QSCALE 2048.0f
#define QINV (1.0f / 2048.0f)

// d_ws layout (u32 units): q_u16 packed pairs [B][SQ][32] (65536 u32), then
// k_u16 packed pairs [B][SK][32] (65536 u32).

__device__ inline unsigned int pk2(float x, float y) {
  int xi = (int)rintf(fminf(fmaxf(x, -15.9f), 15.9f) * QSCALE) + 32768;
  int yi = (int)rintf(fminf(fmaxf(y, -15.9f), 15.9f) * QSCALE) + 32768;
  return (unsigned int)(xi & 0xffff) | ((unsigned int)yi << 16);
}

// ---- Kernel 1: quantize q and k to u16 fixed point in d_ws ----
// 32768 uint4 outputs (first 16384 from q, rest from k); grid 128 x 256.
__global__ __launch_bounds__(256) void convert_qk(const float* __restrict__ qg,
                                                  const float* __restrict__ kg,
                                                  unsigned int* __restrict__ w) {
  const int t = blockIdx.x * 256 + threadIdx.x;
  const float4* s4 = (t < 16384) ? (const float4*)qg : (const float4*)kg;
  const int idx = (t < 16384) ? t : (t - 16384);
  float4 a = s4[idx * 2], b = s4[idx * 2 + 1];
  uint4 r;
  r.x = pk2(a.x, a.y);
  r.y = pk2(a.z, a.w);
  r.z = pk2(b.x, b.y);
  r.w = pk2(b.z, b.w);
  ((uint4*)w)[t] = r;
}

__device__ inline int swz(int key) { return key ^ ((key >> 4) & 7); }

// ---- Kernel 2: fused attention. 512 blocks x 512 threads, QB=4 q/block,
// all 1024 keys per block. All 512 blocks resident (2/CU, 16 waves/CU). ----
__global__ __launch_bounds__(512, 4) void manh_main(
    const unsigned int* __restrict__ wsq, const unsigned int* __restrict__ wsk,
    const float* __restrict__ vg, const int* __restrict__ maskg,
    float* __restrict__ outg) {
  __shared__ float4 p4s[SK_];        // 16 KB probs, swizzled key-major [k][4q]
  __shared__ float pv[16][QB][DV_];  // 16 KB chunk partials
  __shared__ float4 redm[8], redl[8];

  const int tid = threadIdx.x;
  const int wid = tid >> 6;
  const int b = blockIdx.x >> 8;
  const int q0 = (blockIdx.x & 255) * QB;
  const int half = tid & 1;   // dim half (32 dims = 4 uint4)
  const int krid = tid >> 1;  // key id within a 256-key pass

  // q fragments: this thread's dim-half of 4 query rows, u16-packed.
  const uint4* qrow = (const uint4*)(wsq + ((size_t)b * SQ_ + q0) * 32);
  uint4 qr[QB][4];
#pragma unroll
  for (int q = 0; q < QB; ++q)
#pragma unroll
    for (int j = 0; j < 4; ++j) qr[q][j] = qrow[q * 8 + half * 4 + j];

  const uint4* krow = (const uint4*)(wsk + (size_t)b * SK_ * 32);
  const int* mb = maskg + (size_t)b * SK_;

  // ---- Phase 1: 4 passes x 256 keys, 2 lanes/key via v_sad_u16 ----
  float sc[2][QB];  // scores of the 2 owned keys
  float lmax[QB];
#pragma unroll
  for (int q = 0; q < QB; ++q) lmax[q] = -INFINITY;
#pragma unroll
  for (int p = 0; p < 4; ++p) {
    const int key = p * 256 + krid;
    uint4 ks[4];
#pragma unroll
    for (int j = 0; j < 4; ++j) ks[j] = krow[(size_t)key * 8 + half * 4 + j];
    unsigned int d[QB] = {0u, 0u, 0u, 0u};
#pragma unroll
    for (int j = 0; j < 4; ++j) {
#pragma unroll
      for (int q = 0; q < QB; ++q) {
        d[q] = __builtin_amdgcn_sad_u16(qr[q][j].x, ks[j].x, d[q]);
        d[q] = __builtin_amdgcn_sad_u16(qr[q][j].y, ks[j].y, d[q]);
        d[q] = __builtin_amdgcn_sad_u16(qr[q][j].z, ks[j].z, d[q]);
        d[q] = __builtin_amdgcn_sad_u16(qr[q][j].w, ks[j].w, d[q]);
      }
    }
#pragma unroll
    for (int q = 0; q < QB; ++q) d[q] += __shfl_xor(d[q], 1, 64);
    if ((p & 1) == half) {  // even lanes own passes 0,2; odd own 1,3
      const int s = p >> 1;
      const int mk = mb[key];
#pragma unroll
      for (int q = 0; q < QB; ++q) {
        float v = mk ? (-(float)d[q] * QINV) : NEGC;
        sc[s][q] = v;
        lmax[q] = fmaxf(lmax[q], v);
      }
    }
  }

  // block max: wave shuffle reduce -> LDS(8 waves) -> broadcast read
#pragma unroll
  for (int off = 32; off > 0; off >>= 1)
#pragma unroll
    for (int q = 0; q < QB; ++q)
      lmax[q] = fmaxf(lmax[q], __shfl_down(lmax[q], off, 64));
  if ((tid & 63) == 0) redm[wid] = make_float4(lmax[0], lmax[1], lmax[2], lmax[3]);
  __syncthreads();
  float m[QB] = {-INFINITY, -INFINITY, -INFINITY, -INFINITY};
#pragma unroll
  for (int w = 0; w < 8; ++w) {
    float4 r = redm[w];
    m[0] = fmaxf(m[0], r.x); m[1] = fmaxf(m[1], r.y);
    m[2] = fmaxf(m[2], r.z); m[3] = fmaxf(m[3], r.w);
  }

  // exp + store probs (swizzled) + block sum
  float lsum[QB] = {0.f, 0.f, 0.f, 0.f};
#pragma unroll
  for (int s = 0; s < 2; ++s) {
    const int key = (2 * s + half) * 256 + krid;
    float4 e;
    e.x = __expf(sc[s][0] - m[0]); e.y = __expf(sc[s][1] - m[1]);
    e.z = __expf(sc[s][2] - m[2]); e.w = __expf(sc[s][3] - m[3]);
    lsum[0] += e.x; lsum[1] += e.y; lsum[2] += e.z; lsum[3] += e.w;
    p4s[swz(key)] = e;
  }
#pragma unroll
  for (int off = 32; off > 0; off >>= 1)
#pragma unroll
    for (int q = 0; q < QB; ++q) lsum[q] += __shfl_down(lsum[q], off, 64);
  if ((tid & 63) == 0) redl[wid] = make_float4(lsum[0], lsum[1], lsum[2], lsum[3]);
  __syncthreads();  // covers p4s + redl

  // ---- Phase 2: PV. 16 dv-cols x 2 subs x 16 chunks; 32 keys/thread ----
  const int col = tid & 15;
  const int sub = (tid >> 4) & 1;
  const int chunk = tid >> 5;
  const float4* vb4 = (const float4*)(vg + (size_t)b * SK_ * DV_);
  float4 acc[QB];
#pragma unroll
  for (int q = 0; q < QB; ++q) acc[q] = make_float4(0.f, 0.f, 0.f, 0.f);
#pragma unroll 4
  for (int t = 0; t < 32; ++t) {
    const int key = chunk + 16 * (sub + 2 * t);
    float4 v4 = vb4[(size_t)key * 16 + col];
    float4 pw = p4s[swz(key)];
    acc[0].x += pw.x * v4.x; acc[0].y += pw.x * v4.y;
    acc[0].z += pw.x * v4.z; acc[0].w += pw.x * v4.w;
    acc[1].x += pw.y * v4.x; acc[1].y += pw.y * v4.y;
    acc[1].z += pw.y * v4.z; acc[1].w += pw.y * v4.w;
    acc[2].x += pw.z * v4.x; acc[2].y += pw.z * v4.y;
    acc[2].z += pw.z * v4.z; acc[2].w += pw.z * v4.w;
    acc[3].x += pw.w * v4.x; acc[3].y += pw.w * v4.y;
    acc[3].z += pw.w * v4.z; acc[3].w += pw.w * v4.w;
  }
  // combine the 2 subs (lane bit 4), then sub==0 lanes hold chunk partials
#pragma unroll
  for (int q = 0; q < QB; ++q) {
    acc[q].x += __shfl_xor(acc[q].x, 16, 64);
    acc[q].y += __shfl_xor(acc[q].y, 16, 64);
    acc[q].z += __shfl_xor(acc[q].z, 16, 64);
    acc[q].w += __shfl_xor(acc[q].w, 16, 64);
  }
  if (sub == 0) {
#pragma unroll
    for (int q = 0; q < QB; ++q) ((float4*)&pv[chunk][q][0])[col] = acc[q];
  }
  __syncthreads();

  // final: 256 threads = 4 q x 64 dims; sum 16 chunks, normalize, store
  if (tid < 256) {
    const int q2 = tid >> 6;
    const int d2 = tid & 63;
    float s = 0.f;
#pragma unroll
    for (int c = 0; c < 16; ++c) s += pv[c][q2][d2];
    float l = 0.f;
#pragma unroll
    for (int w = 0; w < 8; ++w) l += ((const float*)redl)[w * 4 + q2];
    outg[((size_t)b * SQ_ + q0 + q2) * DV_ + d2] = s / l;
  }
}

extern "C" void kernel_launch(void* const* d_in, const int* in_sizes, int n_in,
                              void* d_out, int out_size, void* d_ws,
                              size_t ws_size, hipStream_t stream) {
  const float* q = (const float*)d_in[0];
  const float* k = (const float*)d_in[1];
  const float* v = (const float*)d_in[2];
  const int* mask = (const int*)d_in[3];
  float* out = (float*)d_out;

  unsigned int* wsq = (unsigned int*)d_ws;
  unsigned int* wsk = wsq + 65536;

  convert_qk<<<dim3(128), dim3(256), 0, stream>>>(q, k, wsq);
  manh_main<<<dim3(B_ * (SQ_ / QB)), dim3(512), 0, stream>>>(wsq, wsk, v, mask,
                                                             out);
}